// Round 1
// baseline (601.972 us; speedup 1.0000x reference)
//
#include <hip/hip_runtime.h>
#include <stdint.h>

typedef unsigned short u16;
typedef __attribute__((ext_vector_type(8))) short short8;
typedef __attribute__((ext_vector_type(4))) float f32x4;
typedef __attribute__((ext_vector_type(4))) u16 us4;
typedef __attribute__((ext_vector_type(8))) u16 us8;

#define DEVI static __device__ __forceinline__

constexpr int BB = 2, TQ = 2048, CD = 2048, NH = 16, HD = 128;
constexpr int STARTP = 1024, SK = 3072;           // total kv length
constexpr int MM = BB * TQ;                       // 4096 rows
constexpr float SM_SCALE = 0.08838834764831845f;  // 128^-0.5

DEVI u16 f2bf(float f) {
  union { float f; unsigned u; } v; v.f = f;
  return (u16)((v.u + 0x7fffu + ((v.u >> 16) & 1u)) >> 16);
}

typedef __attribute__((address_space(1))) const unsigned int gas_u32;
typedef __attribute__((address_space(3))) unsigned int las_u32;

DEVI void gload16(const void* g, void* l) {
  // async global->LDS, 16B per lane; LDS dest = wave-uniform base + lane*16
  __builtin_amdgcn_global_load_lds((gas_u32*)(uintptr_t)g,
                                   (las_u32*)(unsigned)(uintptr_t)l, 16, 0, 0);
}

// ---------------- converts ----------------

__global__ __launch_bounds__(256) void cvt_k(const float* __restrict__ in,
                                             u16* __restrict__ out, int n4) {
  int i = blockIdx.x * 256 + threadIdx.x, st = gridDim.x * 256;
  for (; i < n4; i += st) {
    float4 v = *(const float4*)(in + (size_t)i * 4);
    us4 o = { f2bf(v.x), f2bf(v.y), f2bf(v.z), f2bf(v.w) };
    *(us4*)(out + (size_t)i * 4) = o;
  }
}

// k_cache [bh][1024][128] f32 -> K [bh][3072][128] bf16 rows [0,1024)
__global__ __launch_bounds__(256) void kcache_k(const float* __restrict__ kc,
                                                u16* __restrict__ Kb) {
  constexpr int n4 = BB * NH * STARTP * HD / 4;
  int i = blockIdx.x * 256 + threadIdx.x, st = gridDim.x * 256;
  for (; i < n4; i += st) {
    int e = i * 4;
    int bh = e / (STARTP * HD);
    int rem = e - bh * (STARTP * HD);
    float4 v = *(const float4*)(kc + e);
    us4 o = { f2bf(v.x), f2bf(v.y), f2bf(v.z), f2bf(v.w) };
    *(us4*)(Kb + (size_t)bh * SK * HD + rem) = o;
  }
}

// v_cache [bh][1024][128] f32 -> Vt [bh][128][3072] bf16 cols [0,1024)
__global__ __launch_bounds__(256) void vcache_t_k(const float* __restrict__ vc,
                                                  u16* __restrict__ Vt) {
  __shared__ float tl[64][128];
  const int bh = blockIdx.y;
  const int s0 = blockIdx.x * 64;
  const int tid = threadIdx.x;
  const float* src = vc + ((size_t)bh * STARTP + s0) * HD;
  for (int it = 0; it < 32; ++it) {
    int flat = it * 256 + tid;
    tl[flat >> 7][flat & 127] = src[flat];
  }
  __syncthreads();
  int d = tid >> 1, half = tid & 1;
  u16* dst = Vt + ((size_t)bh * HD + d) * SK + s0 + half * 32;
#pragma unroll
  for (int c = 0; c < 4; ++c) {
    us8 v;
#pragma unroll
    for (int j = 0; j < 8; ++j) v[j] = f2bf(tl[half * 32 + c * 8 + j][d]);
    *(us8*)(dst + c * 8) = v;
  }
}

// ---------------- NT GEMM: C[m][n] = sum_k A[m][k] * W[n][k] ----------------
// MODE 0: fused QKV, blockIdx.y in [0,48): which = y>>4, epilogue scatters
//         to Q[bh][t][d] / K[bh][START+t][d] / Vt[bh][d][START+t] (bf16)
// MODE 1: out proj, writes f32 row-major [4096][2048]
template <int MODE>
__global__ __launch_bounds__(256) void gemm_nt(
    const u16* __restrict__ A, const u16* __restrict__ W0,
    const u16* __restrict__ W1, const u16* __restrict__ W2,
    u16* __restrict__ Qb, u16* __restrict__ Kb, u16* __restrict__ Vtb,
    float* __restrict__ Co) {
  __shared__ __align__(16) u16 Alds[128 * 32];
  __shared__ __align__(16) u16 Blds[128 * 32];
  const int tid = threadIdx.x, lane = tid & 63, w = tid >> 6;
  const int wr = w >> 1, wc = w & 1;
  const int l15 = lane & 15, l4 = lane >> 4;
  const int m0 = blockIdx.x * 128;
  const int tn = blockIdx.y;
  const u16* Wp;
  int which = 0, nb;
  if (MODE == 0) {
    which = tn >> 4;
    nb = (tn & 15) * 128;
    Wp = which == 0 ? W0 : (which == 1 ? W1 : W2);
  } else {
    nb = tn * 128;
    Wp = W0;
  }

  const char* Ab = (const char*)(A + (size_t)m0 * CD);
  const char* Wb = (const char*)(Wp + (size_t)nb * CD);

  f32x4 acc[4][4] = {};

  for (int kt = 0; kt < CD * 2; kt += 64) {  // byte offset along K
    __syncthreads();
#pragma unroll
    for (int c = 0; c < 2; ++c) {
      int o = (w * 2 + c) * 1024 + lane * 16;
      int row = o >> 6, ib = o & 63;
      gload16(Ab + (size_t)row * 4096 + kt + ib, (char*)Alds + o);
      gload16(Wb + (size_t)row * 4096 + kt + ib, (char*)Blds + o);
    }
    asm volatile("s_waitcnt vmcnt(0)" ::: "memory");
    __syncthreads();
    short8 af[4], bfr[4];
#pragma unroll
    for (int i = 0; i < 4; ++i) {
      af[i]  = *(const short8*)((const char*)Alds + (wr * 64 + i * 16 + l15) * 64 + l4 * 16);
      bfr[i] = *(const short8*)((const char*)Blds + (wc * 64 + i * 16 + l15) * 64 + l4 * 16);
    }
#pragma unroll
    for (int i = 0; i < 4; ++i)
#pragma unroll
      for (int j = 0; j < 4; ++j)
        acc[i][j] = __builtin_amdgcn_mfma_f32_16x16x32_bf16(af[i], bfr[j], acc[i][j], 0, 0, 0);
  }

  const int r0 = m0 + wr * 64;
  const int c0 = nb + wc * 64;
#pragma unroll
  for (int i = 0; i < 4; ++i) {
#pragma unroll
    for (int j = 0; j < 4; ++j) {
      int mrow = r0 + i * 16 + l4 * 4;  // +r for r in 0..3
      int ncol = c0 + j * 16 + l15;
      if (MODE == 1) {
#pragma unroll
        for (int r = 0; r < 4; ++r)
          Co[(size_t)(mrow + r) * 2048 + ncol] = acc[i][j][r];
      } else {
        int b = mrow >> 11;
        int t = mrow & 2047;
        int h = ncol >> 7, d = ncol & 127;
        int bh = b * NH + h;
        if (which == 0) {
          u16* p = Qb + ((size_t)bh * TQ + t) * HD + d;
#pragma unroll
          for (int r = 0; r < 4; ++r) p[r * HD] = f2bf(acc[i][j][r]);
        } else if (which == 1) {
          u16* p = Kb + ((size_t)bh * SK + STARTP + t) * HD + d;
#pragma unroll
          for (int r = 0; r < 4; ++r) p[r * HD] = f2bf(acc[i][j][r]);
        } else {
          us4 v = { f2bf(acc[i][j][0]), f2bf(acc[i][j][1]),
                    f2bf(acc[i][j][2]), f2bf(acc[i][j][3]) };
          *(us4*)(Vtb + ((size_t)bh * HD + d) * SK + STARTP + t) = v;
        }
      }
    }
  }
}

// ---------------- flash attention ----------------
// block: 128 q rows (4 waves x 32), kv tiles of 64. K LDS [64][128] and
// Vt LDS [128][64] XOR-swizzled via pre-swizzled global source (rule #21).
__global__ __launch_bounds__(256, 2) void attn_k(const u16* __restrict__ Qb,
                                                 const u16* __restrict__ Kb,
                                                 const u16* __restrict__ Vtb,
                                                 u16* __restrict__ AO) {
  __shared__ __align__(16) u16 Klds[64 * 128];
  __shared__ __align__(16) u16 Vlds[128 * 64];
  __shared__ __align__(16) u16 Plds[4][32 * 64];
  const int tid = threadIdx.x, lane = tid & 63, w = tid >> 6;
  const int l15 = lane & 15, l4 = lane >> 4;
  const int qt0 = blockIdx.x * 128;
  const int bh = blockIdx.y;

  // Q fragments in registers: 32 rows per wave
  short8 qf[2][4];
  const u16* Qbase = Qb + ((size_t)bh * TQ + qt0 + w * 32) * HD;
#pragma unroll
  for (int mi = 0; mi < 2; ++mi)
#pragma unroll
    for (int ks = 0; ks < 4; ++ks)
      qf[mi][ks] = *(const short8*)(Qbase + (mi * 16 + l15) * HD + ks * 32 + l4 * 8);

  f32x4 acc[2][8] = {};
  float mrun[2][4], lrun[2][4];
#pragma unroll
  for (int mi = 0; mi < 2; ++mi)
#pragma unroll
    for (int r = 0; r < 4; ++r) { mrun[mi][r] = -__builtin_inff(); lrun[mi][r] = 0.f; }

  const int nfull = (STARTP + qt0) >> 6;  // tiles below this need no mask
  const int ntiles = nfull + 2;
  const char* Kg = (const char*)(Kb + (size_t)bh * SK * HD);
  const char* Vg = (const char*)(Vtb + (size_t)bh * HD * SK);
  char* Pl = (char*)Plds[w];

  for (int tt = 0; tt < ntiles; ++tt) {
    const int s0 = tt << 6;
    __syncthreads();
    // stage K tile [64][128] (16KB contiguous), inverse-swizzled source
#pragma unroll
    for (int c = 0; c < 4; ++c) {
      int o = (w * 4 + c) * 1024 + lane * 16;
      int a = o ^ (((o >> 8) & 7) << 4);
      gload16(Kg + (size_t)s0 * 256 + a, (char*)Klds + o);
    }
    // stage Vt tile [128][64]
#pragma unroll
    for (int c = 0; c < 4; ++c) {
      int o = (w * 4 + c) * 1024 + lane * 16;
      int a = o ^ (((o >> 7) & 7) << 4);
      int row = a >> 7, ib = a & 127;
      gload16(Vg + ((size_t)row * SK + s0) * 2 + ib, (char*)Vlds + o);
    }
    asm volatile("s_waitcnt vmcnt(0)" ::: "memory");
    __syncthreads();

    // S = Q K^T  (32x64 per wave)
    f32x4 sa[2][4] = {};
#pragma unroll
    for (int ks = 0; ks < 4; ++ks) {
      short8 kf[4];
#pragma unroll
      for (int ni = 0; ni < 4; ++ni) {
        int row = l15 + ni * 16;
        int a = row * 256 + ks * 64 + l4 * 16;
        kf[ni] = *(const short8*)((const char*)Klds + (a ^ ((row & 7) << 4)));
      }
#pragma unroll
      for (int mi = 0; mi < 2; ++mi)
#pragma unroll
        for (int ni = 0; ni < 4; ++ni)
          sa[mi][ni] = __builtin_amdgcn_mfma_f32_16x16x32_bf16(qf[mi][ks], kf[ni], sa[mi][ni], 0, 0, 0);
    }

    const bool need_mask = (tt >= nfull);
#pragma unroll
    for (int mi = 0; mi < 2; ++mi)
#pragma unroll
      for (int ni = 0; ni < 4; ++ni)
#pragma unroll
        for (int r = 0; r < 4; ++r) {
          float v = sa[mi][ni][r] * SM_SCALE;
          if (need_mask) {
            int col = s0 + ni * 16 + l15;
            int lim = STARTP + qt0 + w * 32 + mi * 16 + l4 * 4 + r;
            if (col > lim) v = -__builtin_inff();
          }
          sa[mi][ni][r] = v;
        }

    // online softmax, rows fully wave-parallel (16-lane shfl reduce)
#pragma unroll
    for (int mi = 0; mi < 2; ++mi) {
#pragma unroll
      for (int r = 0; r < 4; ++r) {
        float tmax = fmaxf(fmaxf(sa[mi][0][r], sa[mi][1][r]),
                           fmaxf(sa[mi][2][r], sa[mi][3][r]));
        tmax = fmaxf(tmax, __shfl_xor(tmax, 1));
        tmax = fmaxf(tmax, __shfl_xor(tmax, 2));
        tmax = fmaxf(tmax, __shfl_xor(tmax, 4));
        tmax = fmaxf(tmax, __shfl_xor(tmax, 8));
        float mnew = fmaxf(mrun[mi][r], tmax);
        float sf = __expf(mrun[mi][r] - mnew);
        mrun[mi][r] = mnew;
        float rs = 0.f;
#pragma unroll
        for (int ni = 0; ni < 4; ++ni) {
          float p = __expf(sa[mi][ni][r] - mnew);
          sa[mi][ni][r] = p;
          rs += p;
        }
        rs += __shfl_xor(rs, 1);
        rs += __shfl_xor(rs, 2);
        rs += __shfl_xor(rs, 4);
        rs += __shfl_xor(rs, 8);
        lrun[mi][r] = lrun[mi][r] * sf + rs;
#pragma unroll
        for (int ni = 0; ni < 8; ++ni) acc[mi][ni][r] *= sf;
      }
    }

    // P -> wave-private swizzled LDS (bf16)
#pragma unroll
    for (int mi = 0; mi < 2; ++mi)
#pragma unroll
      for (int ni = 0; ni < 4; ++ni)
#pragma unroll
        for (int r = 0; r < 4; ++r) {
          int row = mi * 16 + l4 * 4 + r;
          int col = ni * 16 + l15;
          int a = row * 128 + col * 2;
          *(u16*)(Pl + (a ^ ((row & 7) << 4))) = f2bf(sa[mi][ni][r]);
        }

    // O += P V
#pragma unroll
    for (int ks = 0; ks < 2; ++ks) {
      short8 pf[2], vf[8];
#pragma unroll
      for (int mi = 0; mi < 2; ++mi) {
        int row = l15 + mi * 16;
        int a = row * 128 + ks * 64 + l4 * 16;
        pf[mi] = *(const short8*)(Pl + (a ^ ((row & 7) << 4)));
      }
#pragma unroll
      for (int ni = 0; ni < 8; ++ni) {
        int row = l15 + ni * 16;
        int a = row * 128 + ks * 64 + l4 * 16;
        vf[ni] = *(const short8*)((const char*)Vlds + (a ^ ((row & 7) << 4)));
      }
#pragma unroll
      for (int mi = 0; mi < 2; ++mi)
#pragma unroll
        for (int ni = 0; ni < 8; ++ni)
          acc[mi][ni] = __builtin_amdgcn_mfma_f32_16x16x32_bf16(pf[mi], vf[ni], acc[mi][ni], 0, 0, 0);
    }
  }

  // epilogue: normalize, write AO[b][t][h*128+d] bf16
  const int b = bh >> 4, h = bh & 15;
#pragma unroll
  for (int mi = 0; mi < 2; ++mi) {
#pragma unroll
    for (int r = 0; r < 4; ++r) {
      float inv = 1.f / lrun[mi][r];
      int t = qt0 + w * 32 + mi * 16 + l4 * 4 + r;
      u16* dst = AO + ((size_t)(b * TQ + t)) * CD + h * HD + l15;
#pragma unroll
      for (int ni = 0; ni < 8; ++ni)
        dst[ni * 16] = f2bf(acc[mi][ni][r] * inv);
    }
  }
}

// ---------------- launch ----------------

extern "C" void kernel_launch(void* const* d_in, const int* in_sizes, int n_in,
                              void* d_out, int out_size, void* d_ws, size_t ws_size,
                              hipStream_t stream) {
  const float* x  = (const float*)d_in[0];
  const float* kc = (const float*)d_in[1];
  const float* vc = (const float*)d_in[2];
  const float* wq = (const float*)d_in[3];
  const float* wk = (const float*)d_in[4];
  const float* wv = (const float*)d_in[5];
  const float* wo = (const float*)d_in[6];
  float* out = (float*)d_out;
  char* ws = (char*)d_ws;

  // workspace layout (117.4 MB total); AO aliases xbf (xbf dead after QKV GEMM)
  u16* xbf = (u16*)(ws);                       // 16.8 MB [4096][2048]
  u16* AO  = (u16*)(ws);                       // alias
  u16* wqb = (u16*)(ws + 16777216);            // 8.4 MB each
  u16* wkb = (u16*)(ws + 25165824);
  u16* wvb = (u16*)(ws + 33554432);
  u16* wob = (u16*)(ws + 41943040);
  u16* Qb  = (u16*)(ws + 50331648);            // 16.8 MB [32][2048][128]
  u16* Kb  = (u16*)(ws + 67108864);            // 25.2 MB [32][3072][128]
  u16* Vtb = (u16*)(ws + 92274688);            // 25.2 MB [32][128][3072]

  cvt_k<<<2048, 256, 0, stream>>>(x, xbf, MM * CD / 4);
  cvt_k<<<1024, 256, 0, stream>>>(wq, wqb, CD * CD / 4);
  cvt_k<<<1024, 256, 0, stream>>>(wk, wkb, CD * CD / 4);
  cvt_k<<<1024, 256, 0, stream>>>(wv, wvb, CD * CD / 4);
  cvt_k<<<1024, 256, 0, stream>>>(wo, wob, CD * CD / 4);
  kcache_k<<<2048, 256, 0, stream>>>(kc, Kb);
  vcache_t_k<<<dim3(16, 32), 256, 0, stream>>>(vc, Vtb);

  gemm_nt<0><<<dim3(32, 48), 256, 0, stream>>>(xbf, wqb, wkb, wvb, Qb, Kb, Vtb, nullptr);
  attn_k<<<dim3(16, 32), 256, 0, stream>>>(Qb, Kb, Vtb, AO);
  gemm_nt<1><<<dim3(32, 16), 256, 0, stream>>>(AO, wob, nullptr, nullptr,
                                               nullptr, nullptr, nullptr, out);
}

// Round 2
// 502.340 us; speedup vs baseline: 1.1983x; 1.1983x over previous
//
#include <hip/hip_runtime.h>
#include <stdint.h>

typedef unsigned short u16;
typedef __attribute__((ext_vector_type(8))) short short8;
typedef __attribute__((ext_vector_type(4))) float f32x4;
typedef __attribute__((ext_vector_type(4))) u16 us4;
typedef __attribute__((ext_vector_type(8))) u16 us8;

#define DEVI static __device__ __forceinline__

constexpr int BB = 2, TQ = 2048, CD = 2048, NH = 16, HD = 128;
constexpr int STARTP = 1024, SK = 3072;           // total kv length
constexpr int MM = BB * TQ;                       // 4096 rows
constexpr float SM_SCALE = 0.08838834764831845f;  // 128^-0.5
constexpr float QSL2 = SM_SCALE * 1.4426950408889634f;  // log2 domain

DEVI u16 f2bf(float f) {
  union { float f; unsigned u; } v; v.f = f;
  return (u16)((v.u + 0x7fffu + ((v.u >> 16) & 1u)) >> 16);
}

typedef __attribute__((address_space(1))) const unsigned int gas_u32;
typedef __attribute__((address_space(3))) unsigned int las_u32;

DEVI void gload16(const void* g, void* l) {
  __builtin_amdgcn_global_load_lds((gas_u32*)(uintptr_t)g,
                                   (las_u32*)(unsigned)(uintptr_t)l, 16, 0, 0);
}

// ---------------- converts ----------------

__global__ __launch_bounds__(256) void cvt_k(const float* __restrict__ in,
                                             u16* __restrict__ out, int n4) {
  int i = blockIdx.x * 256 + threadIdx.x, st = gridDim.x * 256;
  for (; i < n4; i += st) {
    float4 v = *(const float4*)(in + (size_t)i * 4);
    us4 o = { f2bf(v.x), f2bf(v.y), f2bf(v.z), f2bf(v.w) };
    *(us4*)(out + (size_t)i * 4) = o;
  }
}

__global__ __launch_bounds__(256) void kcache_k(const float* __restrict__ kc,
                                                u16* __restrict__ Kb) {
  constexpr int n4 = BB * NH * STARTP * HD / 4;
  int i = blockIdx.x * 256 + threadIdx.x, st = gridDim.x * 256;
  for (; i < n4; i += st) {
    int e = i * 4;
    int bh = e / (STARTP * HD);
    int rem = e - bh * (STARTP * HD);
    float4 v = *(const float4*)(kc + e);
    us4 o = { f2bf(v.x), f2bf(v.y), f2bf(v.z), f2bf(v.w) };
    *(us4*)(Kb + (size_t)bh * SK * HD + rem) = o;
  }
}

__global__ __launch_bounds__(256) void vcache_t_k(const float* __restrict__ vc,
                                                  u16* __restrict__ Vt) {
  __shared__ float tl[64][128];
  const int bh = blockIdx.y;
  const int s0 = blockIdx.x * 64;
  const int tid = threadIdx.x;
  const float* src = vc + ((size_t)bh * STARTP + s0) * HD;
  for (int it = 0; it < 32; ++it) {
    int flat = it * 256 + tid;
    tl[flat >> 7][flat & 127] = src[flat];
  }
  __syncthreads();
  int d = tid >> 1, half = tid & 1;
  u16* dst = Vt + ((size_t)bh * HD + d) * SK + s0 + half * 32;
#pragma unroll
  for (int c = 0; c < 4; ++c) {
    us8 v;
#pragma unroll
    for (int j = 0; j < 8; ++j) v[j] = f2bf(tl[half * 32 + c * 8 + j][d]);
    *(us8*)(dst + c * 8) = v;
  }
}

// ---------------- NT GEMM (m97 structure, unchanged) ----------------
template <int MODE>
__global__ __launch_bounds__(256) void gemm_nt(
    const u16* __restrict__ A, const u16* __restrict__ W0,
    const u16* __restrict__ W1, const u16* __restrict__ W2,
    u16* __restrict__ Qb, u16* __restrict__ Kb, u16* __restrict__ Vtb,
    float* __restrict__ Co) {
  __shared__ __align__(16) u16 Alds[128 * 32];
  __shared__ __align__(16) u16 Blds[128 * 32];
  const int tid = threadIdx.x, lane = tid & 63, w = tid >> 6;
  const int wr = w >> 1, wc = w & 1;
  const int l15 = lane & 15, l4 = lane >> 4;
  const int m0 = blockIdx.x * 128;
  const int tn = blockIdx.y;
  const u16* Wp;
  int which = 0, nb;
  if (MODE == 0) {
    which = tn >> 4;
    nb = (tn & 15) * 128;
    Wp = which == 0 ? W0 : (which == 1 ? W1 : W2);
  } else {
    nb = tn * 128;
    Wp = W0;
  }

  const char* Ab = (const char*)(A + (size_t)m0 * CD);
  const char* Wb = (const char*)(Wp + (size_t)nb * CD);

  f32x4 acc[4][4] = {};

  for (int kt = 0; kt < CD * 2; kt += 64) {
    __syncthreads();
#pragma unroll
    for (int c = 0; c < 2; ++c) {
      int o = (w * 2 + c) * 1024 + lane * 16;
      int row = o >> 6, ib = o & 63;
      gload16(Ab + (size_t)row * 4096 + kt + ib, (char*)Alds + o);
      gload16(Wb + (size_t)row * 4096 + kt + ib, (char*)Blds + o);
    }
    asm volatile("s_waitcnt vmcnt(0)" ::: "memory");
    __syncthreads();
    short8 af[4], bfr[4];
#pragma unroll
    for (int i = 0; i < 4; ++i) {
      af[i]  = *(const short8*)((const char*)Alds + (wr * 64 + i * 16 + l15) * 64 + l4 * 16);
      bfr[i] = *(const short8*)((const char*)Blds + (wc * 64 + i * 16 + l15) * 64 + l4 * 16);
    }
#pragma unroll
    for (int i = 0; i < 4; ++i)
#pragma unroll
      for (int j = 0; j < 4; ++j)
        acc[i][j] = __builtin_amdgcn_mfma_f32_16x16x32_bf16(af[i], bfr[j], acc[i][j], 0, 0, 0);
  }

  const int r0 = m0 + wr * 64;
  const int c0 = nb + wc * 64;
#pragma unroll
  for (int i = 0; i < 4; ++i) {
#pragma unroll
    for (int j = 0; j < 4; ++j) {
      int mrow = r0 + i * 16 + l4 * 4;
      int ncol = c0 + j * 16 + l15;
      if (MODE == 1) {
#pragma unroll
        for (int r = 0; r < 4; ++r)
          Co[(size_t)(mrow + r) * 2048 + ncol] = acc[i][j][r];
      } else {
        int b = mrow >> 11;
        int t = mrow & 2047;
        int h = ncol >> 7, d = ncol & 127;
        int bh = b * NH + h;
        if (which == 0) {
          u16* p = Qb + ((size_t)bh * TQ + t) * HD + d;
#pragma unroll
          for (int r = 0; r < 4; ++r) p[r * HD] = f2bf(acc[i][j][r]);
        } else if (which == 1) {
          u16* p = Kb + ((size_t)bh * SK + STARTP + t) * HD + d;
#pragma unroll
          for (int r = 0; r < 4; ++r) p[r * HD] = f2bf(acc[i][j][r]);
        } else {
          us4 v = { f2bf(acc[i][j][0]), f2bf(acc[i][j][1]),
                    f2bf(acc[i][j][2]), f2bf(acc[i][j][3]) };
          *(us4*)(Vtb + ((size_t)bh * HD + d) * SK + STARTP + t) = v;
        }
      }
    }
  }
}

// ---------------- flash attention v2 ----------------
// Block = 4 waves x 16 q-rows (QBLK=64); processes the PAIR of q-tiles
// (qp, 31-qp) -> exactly 65 KV tiles per block (perfect load balance).
// K/V double-buffered in LDS with prefetch: one vmcnt(0)+barrier per tile.
// Softmax in log2 domain + defer-max rescale (THR=11 log2 units).
__global__ __launch_bounds__(256, 2) void attn_k(const u16* __restrict__ Qb,
                                                 const u16* __restrict__ Kb,
                                                 const u16* __restrict__ Vtb,
                                                 u16* __restrict__ AO) {
  __shared__ __align__(16) u16 Klds[2][64 * 128];
  __shared__ __align__(16) u16 Vlds[2][128 * 64];
  __shared__ __align__(16) u16 Plds[4][16 * 64];
  const int tid = threadIdx.x, lane = tid & 63, w = tid >> 6;
  const int l15 = lane & 15, l4 = lane >> 4;
  const int bh = blockIdx.x;       // bh on x: each XCD's L2 serves 4 heads
  const int qp = blockIdx.y;       // 0..15
  const int qt[2] = { qp, 31 - qp };
  const int na = 17 + qp;          // tiles in segment 0
  const int ntot = 65;             // (17+qp) + (48-qp)

  const char* Kg = (const char*)(Kb + (size_t)bh * SK * HD);
  const char* Vg = (const char*)(Vtb + (size_t)bh * HD * SK);
  char* Pl = (char*)Plds[w];

  short8 qf[4];
  f32x4 acc[8] = {};
  float mrun[4], lrun[4];
#pragma unroll
  for (int r = 0; r < 4; ++r) { mrun[r] = -__builtin_inff(); lrun[r] = 0.f; }

  auto LOADQ = [&](int seg) {
    const u16* Qbase = Qb + ((size_t)bh * TQ + qt[seg] * 64 + w * 16 + l15) * HD;
#pragma unroll
    for (int ks = 0; ks < 4; ++ks)
      qf[ks] = *(const short8*)(Qbase + ks * 32 + l4 * 8);
  };

  auto STAGE = [&](int buf, int s0) {
#pragma unroll
    for (int c = 0; c < 4; ++c) {
      int o = (w * 4 + c) * 1024 + lane * 16;
      {
        int a = o ^ (((o >> 8) & 7) << 4);
        gload16(Kg + (size_t)s0 * 256 + a, (char*)Klds[buf] + o);
      }
      {
        int a = o ^ (((o >> 7) & 7) << 4);
        int row = a >> 7, ib = a & 127;
        gload16(Vg + ((size_t)row * SK + s0) * 2 + ib, (char*)Vlds[buf] + o);
      }
    }
  };

  auto EPI = [&](int seg) {
    const int b = bh >> 4, h = bh & 15;
#pragma unroll
    for (int r = 0; r < 4; ++r) {
      float inv = 1.f / lrun[r];
      int t = qt[seg] * 64 + w * 16 + l4 * 4 + r;
      u16* dst = AO + ((size_t)(b * TQ + t)) * CD + h * HD + l15;
#pragma unroll
      for (int ni = 0; ni < 8; ++ni)
        dst[ni * 16] = f2bf(acc[ni][r] * inv);
    }
  };

  LOADQ(0);
  STAGE(0, 0);
  int cur = 0;

  for (int t = 0; t < ntot; ++t) {
    asm volatile("s_waitcnt vmcnt(0)" ::: "memory");
    __syncthreads();

    // prefetch next tile into the other buffer; KV stream restarts at s0=0
    // for segment 1 (Kg/Vg identical across segments)
    if (t + 1 < ntot) {
      int nl = (t + 1 < na) ? (t + 1) : (t + 1 - na);
      STAGE(cur ^ 1, nl << 6);
    }

    if (t == na) {  // segment switch: flush A, reset state, load Q for B
      EPI(0);
#pragma unroll
      for (int ni = 0; ni < 8; ++ni) acc[ni] = f32x4{0.f, 0.f, 0.f, 0.f};
#pragma unroll
      for (int r = 0; r < 4; ++r) { mrun[r] = -__builtin_inff(); lrun[r] = 0.f; }
      LOADQ(1);
    }

    const int loc = (t < na) ? t : t - na;
    const int nseg = (t < na) ? na : ntot - na;
    const bool diag = (loc == nseg - 1);

    // ---- S = Q K^T (16 rows x 64 cols per wave) ----
    f32x4 sa[4] = {};
#pragma unroll
    for (int ks = 0; ks < 4; ++ks) {
      short8 kf[4];
#pragma unroll
      for (int ni = 0; ni < 4; ++ni) {
        int row = l15 + ni * 16;
        int a = row * 256 + ks * 64 + l4 * 16;
        kf[ni] = *(const short8*)((const char*)Klds[cur] + (a ^ ((row & 7) << 4)));
      }
#pragma unroll
      for (int ni = 0; ni < 4; ++ni)
        sa[ni] = __builtin_amdgcn_mfma_f32_16x16x32_bf16(qf[ks], kf[ni], sa[ni], 0, 0, 0);
    }

    // scale into log2 domain + diagonal mask (only last tile of a segment)
#pragma unroll
    for (int ni = 0; ni < 4; ++ni)
#pragma unroll
      for (int r = 0; r < 4; ++r) {
        float v = sa[ni][r] * QSL2;
        if (diag) {
          int c = ni * 16 + l15;
          int rr = w * 16 + l4 * 4 + r;
          if (c > rr) v = -__builtin_inff();
        }
        sa[ni][r] = v;
      }

    // ---- online softmax (rows on (l4,r); reduce over l15 via shfl) ----
    float tmax[4];
    bool need = false;
#pragma unroll
    for (int r = 0; r < 4; ++r) {
      float m_ = fmaxf(fmaxf(sa[0][r], sa[1][r]), fmaxf(sa[2][r], sa[3][r]));
      m_ = fmaxf(m_, __shfl_xor(m_, 1));
      m_ = fmaxf(m_, __shfl_xor(m_, 2));
      m_ = fmaxf(m_, __shfl_xor(m_, 4));
      m_ = fmaxf(m_, __shfl_xor(m_, 8));
      tmax[r] = m_;
      need = need || (m_ > mrun[r] + 11.f);
    }
    if (__any(need)) {  // defer-max: rescale only when max grew >11 l2 units
#pragma unroll
      for (int r = 0; r < 4; ++r) {
        float mn = fmaxf(mrun[r], tmax[r]);
        float sf = __builtin_amdgcn_exp2f(mrun[r] - mn);
        mrun[r] = mn;
        lrun[r] *= sf;
#pragma unroll
        for (int ni = 0; ni < 8; ++ni) acc[ni][r] *= sf;
      }
    }
#pragma unroll
    for (int r = 0; r < 4; ++r) {
      float rs = 0.f;
#pragma unroll
      for (int ni = 0; ni < 4; ++ni) {
        float p = __builtin_amdgcn_exp2f(sa[ni][r] - mrun[r]);
        sa[ni][r] = p;
        rs += p;
      }
      rs += __shfl_xor(rs, 1);
      rs += __shfl_xor(rs, 2);
      rs += __shfl_xor(rs, 4);
      rs += __shfl_xor(rs, 8);
      lrun[r] += rs;
    }

    // ---- P -> wave-private swizzled LDS (bf16) ----
#pragma unroll
    for (int ni = 0; ni < 4; ++ni)
#pragma unroll
      for (int r = 0; r < 4; ++r) {
        int row = l4 * 4 + r;
        int col = ni * 16 + l15;
        int a = row * 128 + col * 2;
        *(u16*)(Pl + (a ^ ((row & 7) << 4))) = f2bf(sa[ni][r]);
      }

    // ---- O += P V ----
#pragma unroll
    for (int ks = 0; ks < 2; ++ks) {
      short8 pf, vf[8];
      {
        int a = l15 * 128 + ks * 64 + l4 * 16;
        pf = *(const short8*)(Pl + (a ^ ((l15 & 7) << 4)));
      }
#pragma unroll
      for (int ni = 0; ni < 8; ++ni) {
        int row = l15 + ni * 16;
        int a = row * 128 + ks * 64 + l4 * 16;
        vf[ni] = *(const short8*)((const char*)Vlds[cur] + (a ^ ((row & 7) << 4)));
      }
#pragma unroll
      for (int ni = 0; ni < 8; ++ni)
        acc[ni] = __builtin_amdgcn_mfma_f32_16x16x32_bf16(pf, vf[ni], acc[ni], 0, 0, 0);
    }

    cur ^= 1;
  }

  EPI(1);
}

// ---------------- launch ----------------

extern "C" void kernel_launch(void* const* d_in, const int* in_sizes, int n_in,
                              void* d_out, int out_size, void* d_ws, size_t ws_size,
                              hipStream_t stream) {
  const float* x  = (const float*)d_in[0];
  const float* kc = (const float*)d_in[1];
  const float* vc = (const float*)d_in[2];
  const float* wq = (const float*)d_in[3];
  const float* wk = (const float*)d_in[4];
  const float* wv = (const float*)d_in[5];
  const float* wo = (const float*)d_in[6];
  float* out = (float*)d_out;
  char* ws = (char*)d_ws;

  u16* xbf = (u16*)(ws);
  u16* AO  = (u16*)(ws);  // alias: xbf dead after QKV GEMM
  u16* wqb = (u16*)(ws + 16777216);
  u16* wkb = (u16*)(ws + 25165824);
  u16* wvb = (u16*)(ws + 33554432);
  u16* wob = (u16*)(ws + 41943040);
  u16* Qb  = (u16*)(ws + 50331648);
  u16* Kb  = (u16*)(ws + 67108864);
  u16* Vtb = (u16*)(ws + 92274688);

  cvt_k<<<2048, 256, 0, stream>>>(x, xbf, MM * CD / 4);
  cvt_k<<<1024, 256, 0, stream>>>(wq, wqb, CD * CD / 4);
  cvt_k<<<1024, 256, 0, stream>>>(wk, wkb, CD * CD / 4);
  cvt_k<<<1024, 256, 0, stream>>>(wv, wvb, CD * CD / 4);
  cvt_k<<<1024, 256, 0, stream>>>(wo, wob, CD * CD / 4);
  kcache_k<<<2048, 256, 0, stream>>>(kc, Kb);
  vcache_t_k<<<dim3(16, 32), 256, 0, stream>>>(vc, Vtb);

  gemm_nt<0><<<dim3(32, 48), 256, 0, stream>>>(xbf, wqb, wkb, wvb, Qb, Kb, Vtb, nullptr);
  attn_k<<<dim3(32, 16), 256, 0, stream>>>(Qb, Kb, Vtb, AO);
  gemm_nt<1><<<dim3(32, 16), 256, 0, stream>>>(AO, wob, nullptr, nullptr,
                                               nullptr, nullptr, nullptr, out);
}